// Round 11
// baseline (400.924 us; speedup 1.0000x reference)
//
#include <hip/hip_runtime.h>
#include <hip/hip_bf16.h>

#define ELL_D 64   // max in-degree slots; Poisson(16) => P(deg>=64) ~ 2e-18/node

typedef __attribute__((ext_vector_type(8))) short short8;
typedef __attribute__((ext_vector_type(8))) unsigned short ushort8;
typedef __attribute__((ext_vector_type(4))) float f32x4;

__device__ __forceinline__ unsigned short f2bf(float f) {
    __hip_bfloat16 h = __float2bfloat16(f);  // RNE
    return *(unsigned short*)&h;
}
__device__ __forceinline__ float bf2f(unsigned short u) {
    unsigned int v = ((unsigned int)u) << 16;
    return __uint_as_float(v);
}

// ---------------- gemm1 body (f32 vector): A(bf16 row-major, unscaled) = x @ W0 ----------------

__device__ __forceinline__ void gemm_body(int bid, const float* __restrict__ H,
                                          const float* __restrict__ W, unsigned short* __restrict__ A,
                                          int N, float4* wl4) {
    int tid = threadIdx.x;
    const float4* __restrict__ W4 = (const float4*)W;
    int tc = tid & 15;
    int tr = tid >> 4;
    int rbase = bid * 64 + tr * 4;

    const float4* __restrict__ H4 = (const float4*)H;
    float acc[4][8] = {};
    int r[4];
#pragma unroll
    for (int j = 0; j < 4; j++) {
        int rr = rbase + j;
        r[j] = (rr < N) ? rr : (N - 1);
    }

    for (int p = 0; p < 2; p++) {
        if (p) __syncthreads();
#pragma unroll
        for (int i = 0; i < 8; i++) wl4[i * 256 + tid] = W4[p * 2048 + i * 256 + tid];
        __syncthreads();
#pragma unroll 4
        for (int k4 = 0; k4 < 16; k4++) {
            union { float4 v; float f[4]; } hu[4];
#pragma unroll
            for (int j = 0; j < 4; j++) hu[j].v = H4[r[j] * 32 + p * 16 + k4];
#pragma unroll
            for (int kk = 0; kk < 4; kk++) {
                float4 w0 = wl4[(k4 * 4 + kk) * 32 + tc];
                float4 w1 = wl4[(k4 * 4 + kk) * 32 + 16 + tc];
#pragma unroll
                for (int j = 0; j < 4; j++) {
                    float h = hu[j].f[kk];
                    acc[j][0] = fmaf(h, w0.x, acc[j][0]);
                    acc[j][1] = fmaf(h, w0.y, acc[j][1]);
                    acc[j][2] = fmaf(h, w0.z, acc[j][2]);
                    acc[j][3] = fmaf(h, w0.w, acc[j][3]);
                    acc[j][4] = fmaf(h, w1.x, acc[j][4]);
                    acc[j][5] = fmaf(h, w1.y, acc[j][5]);
                    acc[j][6] = fmaf(h, w1.z, acc[j][6]);
                    acc[j][7] = fmaf(h, w1.w, acc[j][7]);
                }
            }
        }
    }

    ushort4* __restrict__ A4 = (ushort4*)A;
#pragma unroll
    for (int j = 0; j < 4; j++) {
        int rr = rbase + j;
        if (rr < N) {
            A4[rr * 32 + tc]      = make_ushort4(f2bf(acc[j][0]), f2bf(acc[j][1]), f2bf(acc[j][2]), f2bf(acc[j][3]));
            A4[rr * 32 + 16 + tc] = make_ushort4(f2bf(acc[j][4]), f2bf(acc[j][5]), f2bf(acc[j][6]), f2bf(acc[j][7]));
        }
    }
}

// ---------------- ELL fill (4 edges/thread, positional atomic) ----------------

__device__ __forceinline__ void fill_body(int bid, const int* __restrict__ col, const int* __restrict__ row,
                                          int* __restrict__ cnt, int* __restrict__ ell, int E) {
    int t = bid * 256 + threadIdx.x;
    int base = t * 4;
    if (base + 4 <= E) {
        int4 c4 = *(const int4*)(col + base);
        int4 r4 = *(const int4*)(row + base);
        int p0 = atomicAdd(&cnt[c4.x], 1) & 63;
        int p1 = atomicAdd(&cnt[c4.y], 1) & 63;
        int p2 = atomicAdd(&cnt[c4.z], 1) & 63;
        int p3 = atomicAdd(&cnt[c4.w], 1) & 63;
        ell[c4.x * ELL_D + p0] = r4.x;
        ell[c4.y * ELL_D + p1] = r4.y;
        ell[c4.z * ELL_D + p2] = r4.z;
        ell[c4.w * ELL_D + p3] = r4.w;
    } else {
        for (int e = base; e < E; e++) {
            int c = col[e];
            int pos = atomicAdd(&cnt[c], 1) & 63;
            ell[c * ELL_D + pos] = row[e];
        }
    }
}

__global__ __launch_bounds__(256) void k_fused(const float* __restrict__ H, const float* __restrict__ W,
                                               unsigned short* __restrict__ A,
                                               const int* __restrict__ col, const int* __restrict__ row,
                                               int* __restrict__ cnt, int* __restrict__ ell,
                                               int N, int E, int gb, int fb) {
    __shared__ float4 wl4[2048];  // 32KB (gemm blocks only)
    int half = blockIdx.x >> 1;
    if (!(blockIdx.x & 1)) {
        if (half < gb) gemm_body(half, H, W, A, N, wl4);
    } else {
        if (half < fb) fill_body(half, col, row, cnt, ell, E);
    }
}

// ---------------- W prep: WT (bf16, transposed) for layers 2,3 ----------------
__global__ __launch_bounds__(256) void k_prep_wt(const float* __restrict__ W1, const float* __restrict__ W2,
                                                 unsigned short* __restrict__ WT1, unsigned short* __restrict__ WT2) {
    const float* W = blockIdx.x ? W2 : W1;
    unsigned short* WT = blockIdx.x ? WT2 : WT1;
    for (int i = threadIdx.x; i < 16384; i += 256) {
        int c = i >> 7, k = i & 127;
        WT[i] = f2bf(W[k * 128 + c]);  // WT[c][k] = W[k][c]
    }
}

// ---------------- scaleA + dinv + ELL pad (self slot + N-sentinels to multiple of 8) ----------------
// Also zeroes sentinel row N of A.

__global__ __launch_bounds__(256) void k_scaleA_pad(const int* __restrict__ cnt, float* __restrict__ dinv,
                                                    unsigned short* __restrict__ A, int* __restrict__ ell, int N) {
    int node = blockIdx.x * 8 + (threadIdx.x >> 5);
    int li = threadIdx.x & 31;
    if (node < N) {
        int deg = cnt[node];
        float dn = 1.0f / sqrtf((float)(deg + 1));
        if (deg > 63) deg = 63;
        if (li == 0) dinv[node] = dn;
        ushort4* Ap = (ushort4*)A + (size_t)node * 32 + li;
        ushort4 v = *Ap;
        v.x = f2bf(bf2f(v.x) * dn);
        v.y = f2bf(bf2f(v.y) * dn);
        v.z = f2bf(bf2f(v.z) * dn);
        v.w = f2bf(bf2f(v.w) * dn);
        *Ap = v;
        int pend = (deg + 8) & ~7;  // slots: deg edges + self + sentinels, multiple of 8
        if (pend > 64) pend = 64;
        int* er = ell + (size_t)node * ELL_D;
        if (li == 0) er[deg] = node;                               // virtual self edge
        else if (li < 8 && deg + li < pend) er[deg + li] = N;      // zero-row sentinels
    }
    if (blockIdx.x == 0 && threadIdx.x < 32) {
        ((ushort4*)A)[(size_t)N * 32 + threadIdx.x] = make_ushort4(0, 0, 0, 0);
    }
}

// ---------------- Aggregation: quarter-wave per node (16 lanes x 16B), 8-deep gather loop ----------------
// A rows pre-scaled by dinv[src]; row N = zeros. Bout[n] = bf16(relu(dinv[n]*sum + bias)).
// 32 row-gathers in flight per wave; no cross-lane reduction (lane owns 8 cols end-to-end).

__global__ __launch_bounds__(256) void k_agg(const unsigned short* __restrict__ Ain, const int* __restrict__ cnt,
                                             const int* __restrict__ ell, const float* __restrict__ dinv,
                                             const float* __restrict__ bias, unsigned short* __restrict__ Bout, int N) {
    int tid = threadIdx.x;
    int li = tid & 15;                    // lane within quarter-wave: cols li*8..li*8+7
    int n = blockIdx.x * 16 + (tid >> 4); // quarter-wave index = node
    if (n >= N) return;
    const ushort8* __restrict__ A8 = (const ushort8*)Ain;
    int deg = cnt[n];
    if (deg > 63) deg = 63;
    int pend = (deg + 8) & ~7;
    if (pend > 64) pend = 64;
    int nq = pend >> 2;  // even
    const int4* __restrict__ l4 = (const int4*)(ell + (size_t)n * ELL_D);

    float a0 = 0.f, a1 = 0.f, a2 = 0.f, a3 = 0.f, a4 = 0.f, a5 = 0.f, a6 = 0.f, a7 = 0.f;
    for (int q = 0; q < nq; q += 2) {
        int4 qa = l4[q], qb = l4[q + 1];
        ushort8 v0 = A8[(size_t)qa.x * 16 + li];
        ushort8 v1 = A8[(size_t)qa.y * 16 + li];
        ushort8 v2 = A8[(size_t)qa.z * 16 + li];
        ushort8 v3 = A8[(size_t)qa.w * 16 + li];
        ushort8 v4 = A8[(size_t)qb.x * 16 + li];
        ushort8 v5 = A8[(size_t)qb.y * 16 + li];
        ushort8 v6 = A8[(size_t)qb.z * 16 + li];
        ushort8 v7 = A8[(size_t)qb.w * 16 + li];
        a0 += (bf2f(v0[0]) + bf2f(v1[0])) + (bf2f(v2[0]) + bf2f(v3[0])) + (bf2f(v4[0]) + bf2f(v5[0])) + (bf2f(v6[0]) + bf2f(v7[0]));
        a1 += (bf2f(v0[1]) + bf2f(v1[1])) + (bf2f(v2[1]) + bf2f(v3[1])) + (bf2f(v4[1]) + bf2f(v5[1])) + (bf2f(v6[1]) + bf2f(v7[1]));
        a2 += (bf2f(v0[2]) + bf2f(v1[2])) + (bf2f(v2[2]) + bf2f(v3[2])) + (bf2f(v4[2]) + bf2f(v5[2])) + (bf2f(v6[2]) + bf2f(v7[2]));
        a3 += (bf2f(v0[3]) + bf2f(v1[3])) + (bf2f(v2[3]) + bf2f(v3[3])) + (bf2f(v4[3]) + bf2f(v5[3])) + (bf2f(v6[3]) + bf2f(v7[3]));
        a4 += (bf2f(v0[4]) + bf2f(v1[4])) + (bf2f(v2[4]) + bf2f(v3[4])) + (bf2f(v4[4]) + bf2f(v5[4])) + (bf2f(v6[4]) + bf2f(v7[4]));
        a5 += (bf2f(v0[5]) + bf2f(v1[5])) + (bf2f(v2[5]) + bf2f(v3[5])) + (bf2f(v4[5]) + bf2f(v5[5])) + (bf2f(v6[5]) + bf2f(v7[5]));
        a6 += (bf2f(v0[6]) + bf2f(v1[6])) + (bf2f(v2[6]) + bf2f(v3[6])) + (bf2f(v4[6]) + bf2f(v5[6])) + (bf2f(v6[6]) + bf2f(v7[6]));
        a7 += (bf2f(v0[7]) + bf2f(v1[7])) + (bf2f(v2[7]) + bf2f(v3[7])) + (bf2f(v4[7]) + bf2f(v5[7])) + (bf2f(v6[7]) + bf2f(v7[7]));
    }
    float dn = dinv[n];
    const float4* __restrict__ b4 = (const float4*)bias;
    float4 bl0 = b4[li * 2], bl1 = b4[li * 2 + 1];
    ushort8 o;
    o[0] = f2bf(fmaxf(fmaf(a0, dn, bl0.x), 0.f));
    o[1] = f2bf(fmaxf(fmaf(a1, dn, bl0.y), 0.f));
    o[2] = f2bf(fmaxf(fmaf(a2, dn, bl0.z), 0.f));
    o[3] = f2bf(fmaxf(fmaf(a3, dn, bl0.w), 0.f));
    o[4] = f2bf(fmaxf(fmaf(a4, dn, bl1.x), 0.f));
    o[5] = f2bf(fmaxf(fmaf(a5, dn, bl1.y), 0.f));
    o[6] = f2bf(fmaxf(fmaf(a6, dn, bl1.z), 0.f));
    o[7] = f2bf(fmaxf(fmaf(a7, dn, bl1.w), 0.f));
    ((ushort8*)Bout)[(size_t)n * 16 + li] = o;
}

// ---------------- MFMA GEMM (layers 2,3): A' = bf16((Bb @ W) * dinv[row]) ----------------

__global__ __launch_bounds__(256) void k_gemm_mfma(const unsigned short* __restrict__ H,
                                                   const unsigned short* __restrict__ WT,
                                                   const float* __restrict__ dinv,
                                                   unsigned short* __restrict__ A, int N) {
    __shared__ float ep[4 * 16 * 132];  // per-wave 16x128 f32, row stride 132
    int tid = threadIdx.x, w = tid >> 6, l = tid & 63;
    int rbase = blockIdx.x * 64 + w * 16;
    int lrow = l & 15, lk = l >> 4;

    int r = rbase + lrow;
    if (r >= N) r = N - 1;
    const short8* __restrict__ Hp = (const short8*)(H + (size_t)r * 128);
    short8 af[4];
#pragma unroll
    for (int kc = 0; kc < 4; kc++) af[kc] = Hp[kc * 4 + lk];

    f32x4 acc[8];
#pragma unroll
    for (int t = 0; t < 8; t++) {
        f32x4 a = {0.f, 0.f, 0.f, 0.f};
        const short8* __restrict__ Wp = (const short8*)(WT + (size_t)(t * 16 + lrow) * 128);
#pragma unroll
        for (int kc = 0; kc < 4; kc++) {
            short8 bf = Wp[kc * 4 + lk];
            a = __builtin_amdgcn_mfma_f32_16x16x32_bf16(af[kc], bf, a, 0, 0, 0);
        }
        acc[t] = a;
    }

    float* base = ep + w * 2112;
#pragma unroll
    for (int t = 0; t < 8; t++)
#pragma unroll
        for (int j = 0; j < 4; j++)
            base[(4 * lk + j) * 132 + t * 16 + lrow] = acc[t][j];
    __syncthreads();

    int row16 = l >> 2, c0 = (l & 3) * 32;
    int orow = rbase + row16;
    if (orow < N) {
        float dn = dinv[orow];
        const float* src = base + row16 * 132 + c0;
        unsigned short* dst = A + (size_t)orow * 128 + c0;
#pragma unroll
        for (int q = 0; q < 4; q++) {
            union { short8 s8; unsigned short u[8]; } pk;
#pragma unroll
            for (int e = 0; e < 8; e++) pk.u[e] = f2bf(src[q * 8 + e] * dn);
            *(short8*)(dst + q * 8) = pk.s8;
        }
    }
}

// ---------------- Pool (mean per graph, sorted batch) + head; B is bf16 ----------------

__global__ __launch_bounds__(512) void k_pool(const unsigned short* __restrict__ B, const int* __restrict__ batch,
                                              const float* __restrict__ Wl, const float* __restrict__ bl,
                                              float* __restrict__ out, int N) {
    int g = blockIdx.x;
    int tid = threadIdx.x;
    int k = tid & 127, h = tid >> 7;  // h in 0..3
    __shared__ int se[2];
    __shared__ float red[4][128];
    if (tid < 2) {
        int target = g + tid;  // lower_bound(batch, target)
        int lo = 0, hi = N;
        while (lo < hi) {
            int mid = (lo + hi) >> 1;
            if (batch[mid] < target) lo = mid + 1; else hi = mid;
        }
        se[tid] = lo;
    }
    __syncthreads();
    int start = se[0], end = se[1];
    float s = 0.f;
    for (int n = start + h; n < end; n += 4) s += bf2f(B[n * 128 + k]);
    red[h][k] = s;
    __syncthreads();
    if (h == 0) {
        float tot = red[0][k] + red[1][k] + red[2][k] + red[3][k];
        int cg = end - start;
        red[0][k] = tot / (float)(cg > 1 ? cg : 1);
    }
    __syncthreads();
    if (tid < 10) {
        float o = bl[tid];
        for (int j = 0; j < 128; j++) o = fmaf(red[0][j], Wl[j * 10 + tid], o);
        out[g * 10 + tid] = o;
    }
}

// ---------------- launch ----------------

extern "C" void kernel_launch(void* const* d_in, const int* in_sizes, int n_in,
                              void* d_out, int out_size, void* d_ws, size_t ws_size,
                              hipStream_t stream) {
    const float* x  = (const float*)d_in[0];
    const int* eidx = (const int*)d_in[1];
    const int* batch = (const int*)d_in[2];
    const float* W0 = (const float*)d_in[3];
    const float* b0 = (const float*)d_in[4];
    const float* W1 = (const float*)d_in[5];
    const float* b1 = (const float*)d_in[6];
    const float* W2 = (const float*)d_in[7];
    const float* b2 = (const float*)d_in[8];
    const float* Wl = (const float*)d_in[9];
    const float* bl = (const float*)d_in[10];

    int N = in_sizes[0] / 128;
    int E = in_sizes[1] / 2;
    int G = out_size / 10;
    const int* row = eidx;      // edge_index[0] = source
    const int* col = eidx + E;  // edge_index[1] = target

    char* w = (char*)d_ws;
    auto carve = [&](size_t bytes) -> void* {
        void* p = (void*)w;
        w += (bytes + 511) & ~(size_t)511;
        return p;
    };
    unsigned short* A  = (unsigned short*)carve((size_t)(N + 1) * 128 * 2);  // bf16, +zero row N
    unsigned short* Bb = (unsigned short*)carve((size_t)N * 128 * 2);        // bf16
    int*   cnt  = (int*)carve((size_t)N * 4);
    float* dinv = (float*)carve((size_t)N * 4);
    int*   ell  = (int*)carve((size_t)N * ELL_D * 4);
    unsigned short* WT1 = (unsigned short*)carve(16384 * 2);
    unsigned short* WT2 = (unsigned short*)carve(16384 * 2);

    int gb = (N + 63) / 64;
    int ft = (E + 3) / 4;
    int fb = (ft + 255) / 256;
    int M  = (gb > fb) ? gb : fb;

    hipMemsetAsync(cnt, 0, (size_t)N * 4, stream);
    k_prep_wt<<<2, 256, 0, stream>>>(W1, W2, WT1, WT2);
    // layer-1 gemm (f32 vector) overlapped with ELL fill
    k_fused<<<2 * M, 256, 0, stream>>>(x, W0, A, col, row, cnt, ell, N, E, gb, fb);
    // dinv + scale A + pad ELL (self + N-sentinels to x8) + zero row N
    k_scaleA_pad<<<(N + 7) / 8, 256, 0, stream>>>(cnt, dinv, A, ell, N);

    int ab = (N + 15) / 16;
    int mb = (N + 63) / 64;
    k_agg<<<ab, 256, 0, stream>>>(A, cnt, ell, dinv, b0, Bb, N);
    // layer 2
    k_gemm_mfma<<<mb, 256, 0, stream>>>(Bb, WT1, dinv, A, N);
    k_agg<<<ab, 256, 0, stream>>>(A, cnt, ell, dinv, b1, Bb, N);
    // layer 3
    k_gemm_mfma<<<mb, 256, 0, stream>>>(Bb, WT2, dinv, A, N);
    k_agg<<<ab, 256, 0, stream>>>(A, cnt, ell, dinv, b2, Bb, N);
    // pool + head
    k_pool<<<G, 512, 0, stream>>>(Bb, batch, Wl, bl, (float*)d_out, N);
}

// Round 12
// 380.218 us; speedup vs baseline: 1.0545x; 1.0545x over previous
//
#include <hip/hip_runtime.h>
#include <hip/hip_bf16.h>

#define ELL_D 64   // max in-degree slots; Poisson(16) => P(deg>=64) ~ 2e-18/node

typedef __attribute__((ext_vector_type(8))) short short8;
typedef __attribute__((ext_vector_type(8))) unsigned short ushort8;
typedef __attribute__((ext_vector_type(4))) float f32x4;

__device__ __forceinline__ unsigned short f2bf(float f) {
    __hip_bfloat16 h = __float2bfloat16(f);  // RNE
    return *(unsigned short*)&h;
}
__device__ __forceinline__ float bf2f(unsigned short u) {
    unsigned int v = ((unsigned int)u) << 16;
    return __uint_as_float(v);
}

// ---------------- gemm1 body (f32 vector): A(bf16 row-major, unscaled) = x @ W0 ----------------

__device__ __forceinline__ void gemm_body(int bid, const float* __restrict__ H,
                                          const float* __restrict__ W, unsigned short* __restrict__ A,
                                          int N, float4* wl4) {
    int tid = threadIdx.x;
    const float4* __restrict__ W4 = (const float4*)W;
    int tc = tid & 15;
    int tr = tid >> 4;
    int rbase = bid * 64 + tr * 4;

    const float4* __restrict__ H4 = (const float4*)H;
    float acc[4][8] = {};
    int r[4];
#pragma unroll
    for (int j = 0; j < 4; j++) {
        int rr = rbase + j;
        r[j] = (rr < N) ? rr : (N - 1);
    }

    for (int p = 0; p < 2; p++) {
        if (p) __syncthreads();
#pragma unroll
        for (int i = 0; i < 8; i++) wl4[i * 256 + tid] = W4[p * 2048 + i * 256 + tid];
        __syncthreads();
#pragma unroll 4
        for (int k4 = 0; k4 < 16; k4++) {
            union { float4 v; float f[4]; } hu[4];
#pragma unroll
            for (int j = 0; j < 4; j++) hu[j].v = H4[r[j] * 32 + p * 16 + k4];
#pragma unroll
            for (int kk = 0; kk < 4; kk++) {
                float4 w0 = wl4[(k4 * 4 + kk) * 32 + tc];
                float4 w1 = wl4[(k4 * 4 + kk) * 32 + 16 + tc];
#pragma unroll
                for (int j = 0; j < 4; j++) {
                    float h = hu[j].f[kk];
                    acc[j][0] = fmaf(h, w0.x, acc[j][0]);
                    acc[j][1] = fmaf(h, w0.y, acc[j][1]);
                    acc[j][2] = fmaf(h, w0.z, acc[j][2]);
                    acc[j][3] = fmaf(h, w0.w, acc[j][3]);
                    acc[j][4] = fmaf(h, w1.x, acc[j][4]);
                    acc[j][5] = fmaf(h, w1.y, acc[j][5]);
                    acc[j][6] = fmaf(h, w1.z, acc[j][6]);
                    acc[j][7] = fmaf(h, w1.w, acc[j][7]);
                }
            }
        }
    }

    ushort4* __restrict__ A4 = (ushort4*)A;
#pragma unroll
    for (int j = 0; j < 4; j++) {
        int rr = rbase + j;
        if (rr < N) {
            A4[rr * 32 + tc]      = make_ushort4(f2bf(acc[j][0]), f2bf(acc[j][1]), f2bf(acc[j][2]), f2bf(acc[j][3]));
            A4[rr * 32 + 16 + tc] = make_ushort4(f2bf(acc[j][4]), f2bf(acc[j][5]), f2bf(acc[j][6]), f2bf(acc[j][7]));
        }
    }
}

// ---------------- ELL fill (8 edges/thread, positional atomic) ----------------

__device__ __forceinline__ void fill_body(int bid, const int* __restrict__ col, const int* __restrict__ row,
                                          int* __restrict__ cnt, int* __restrict__ ell, int E) {
    int t = bid * 256 + threadIdx.x;
    int base = t * 8;
    if (base + 8 <= E) {
        int4 ca = *(const int4*)(col + base);
        int4 cb = *(const int4*)(col + base + 4);
        int4 ra = *(const int4*)(row + base);
        int4 rb = *(const int4*)(row + base + 4);
        int p0 = atomicAdd(&cnt[ca.x], 1) & 63;
        int p1 = atomicAdd(&cnt[ca.y], 1) & 63;
        int p2 = atomicAdd(&cnt[ca.z], 1) & 63;
        int p3 = atomicAdd(&cnt[ca.w], 1) & 63;
        int p4 = atomicAdd(&cnt[cb.x], 1) & 63;
        int p5 = atomicAdd(&cnt[cb.y], 1) & 63;
        int p6 = atomicAdd(&cnt[cb.z], 1) & 63;
        int p7 = atomicAdd(&cnt[cb.w], 1) & 63;
        ell[ca.x * ELL_D + p0] = ra.x;
        ell[ca.y * ELL_D + p1] = ra.y;
        ell[ca.z * ELL_D + p2] = ra.z;
        ell[ca.w * ELL_D + p3] = ra.w;
        ell[cb.x * ELL_D + p4] = rb.x;
        ell[cb.y * ELL_D + p5] = rb.y;
        ell[cb.z * ELL_D + p6] = rb.z;
        ell[cb.w * ELL_D + p7] = rb.w;
    } else {
        for (int e = base; e < E; e++) {
            int c = col[e];
            int pos = atomicAdd(&cnt[c], 1) & 63;
            ell[c * ELL_D + pos] = row[e];
        }
    }
}

// W prep body (blocks 0,1 of k_fused): WT (bf16, transposed)
__device__ __forceinline__ void prep_wt_body(int which, const float* __restrict__ W1, const float* __restrict__ W2,
                                             unsigned short* __restrict__ WT1, unsigned short* __restrict__ WT2) {
    const float* W = which ? W2 : W1;
    unsigned short* WT = which ? WT2 : WT1;
    for (int i = threadIdx.x; i < 16384; i += 256) {
        int c = i >> 7, k = i & 127;
        WT[i] = f2bf(W[k * 128 + c]);  // WT[c][k] = W[k][c]
    }
}

__global__ __launch_bounds__(256) void k_fused(const float* __restrict__ H, const float* __restrict__ W,
                                               unsigned short* __restrict__ A,
                                               const int* __restrict__ col, const int* __restrict__ row,
                                               int* __restrict__ cnt, int* __restrict__ ell,
                                               const float* __restrict__ W1, const float* __restrict__ W2,
                                               unsigned short* __restrict__ WT1, unsigned short* __restrict__ WT2,
                                               int N, int E, int gb, int fb) {
    __shared__ float4 wl4[2048];  // 32KB (gemm blocks only)
    int b = blockIdx.x;
    if (b < 2) { prep_wt_body(b, W1, W2, WT1, WT2); return; }
    b -= 2;
    int half = b >> 1;
    if (!(b & 1)) {
        if (half < gb) gemm_body(half, H, W, A, N, wl4);
    } else {
        if (half < fb) fill_body(half, col, row, cnt, ell, E);
    }
}

// ---------------- scaleA + dinv + ELL pad (self slot + N-sentinels to multiple of 8) ----------------
// Also zeroes sentinel row N of A.

__global__ __launch_bounds__(256) void k_scaleA_pad(const int* __restrict__ cnt, float* __restrict__ dinv,
                                                    unsigned short* __restrict__ A, int* __restrict__ ell, int N) {
    int node = blockIdx.x * 8 + (threadIdx.x >> 5);
    int li = threadIdx.x & 31;
    if (node < N) {
        int deg = cnt[node];
        float dn = 1.0f / sqrtf((float)(deg + 1));
        if (deg > 63) deg = 63;
        if (li == 0) dinv[node] = dn;
        ushort4* Ap = (ushort4*)A + (size_t)node * 32 + li;
        ushort4 v = *Ap;
        v.x = f2bf(bf2f(v.x) * dn);
        v.y = f2bf(bf2f(v.y) * dn);
        v.z = f2bf(bf2f(v.z) * dn);
        v.w = f2bf(bf2f(v.w) * dn);
        *Ap = v;
        int pend = (deg + 8) & ~7;  // slots: deg edges + self + sentinels, multiple of 8
        if (pend > 64) pend = 64;
        int* er = ell + (size_t)node * ELL_D;
        if (li == 0) er[deg] = node;                               // virtual self edge
        else if (li < 8 && deg + li < pend) er[deg + li] = N;      // zero-row sentinels
    }
    if (blockIdx.x == 0 && threadIdx.x < 32) {
        ((ushort4*)A)[(size_t)N * 32 + threadIdx.x] = make_ushort4(0, 0, 0, 0);
    }
}

// ---------------- Aggregation: quarter-wave per node (16 lanes x 16B), 8-deep gather loop ----------------

__global__ __launch_bounds__(256) void k_agg(const unsigned short* __restrict__ Ain, const int* __restrict__ cnt,
                                             const int* __restrict__ ell, const float* __restrict__ dinv,
                                             const float* __restrict__ bias, unsigned short* __restrict__ Bout, int N) {
    int tid = threadIdx.x;
    int li = tid & 15;                    // lane within quarter-wave: cols li*8..li*8+7
    int n = blockIdx.x * 16 + (tid >> 4); // quarter-wave index = node
    if (n >= N) return;
    const ushort8* __restrict__ A8 = (const ushort8*)Ain;
    int deg = cnt[n];
    if (deg > 63) deg = 63;
    int pend = (deg + 8) & ~7;
    if (pend > 64) pend = 64;
    int nq = pend >> 2;  // even
    const int4* __restrict__ l4 = (const int4*)(ell + (size_t)n * ELL_D);

    float a0 = 0.f, a1 = 0.f, a2 = 0.f, a3 = 0.f, a4 = 0.f, a5 = 0.f, a6 = 0.f, a7 = 0.f;
    for (int q = 0; q < nq; q += 2) {
        int4 qa = l4[q], qb = l4[q + 1];
        ushort8 v0 = A8[(size_t)qa.x * 16 + li];
        ushort8 v1 = A8[(size_t)qa.y * 16 + li];
        ushort8 v2 = A8[(size_t)qa.z * 16 + li];
        ushort8 v3 = A8[(size_t)qa.w * 16 + li];
        ushort8 v4 = A8[(size_t)qb.x * 16 + li];
        ushort8 v5 = A8[(size_t)qb.y * 16 + li];
        ushort8 v6 = A8[(size_t)qb.z * 16 + li];
        ushort8 v7 = A8[(size_t)qb.w * 16 + li];
        a0 += (bf2f(v0[0]) + bf2f(v1[0])) + (bf2f(v2[0]) + bf2f(v3[0])) + (bf2f(v4[0]) + bf2f(v5[0])) + (bf2f(v6[0]) + bf2f(v7[0]));
        a1 += (bf2f(v0[1]) + bf2f(v1[1])) + (bf2f(v2[1]) + bf2f(v3[1])) + (bf2f(v4[1]) + bf2f(v5[1])) + (bf2f(v6[1]) + bf2f(v7[1]));
        a2 += (bf2f(v0[2]) + bf2f(v1[2])) + (bf2f(v2[2]) + bf2f(v3[2])) + (bf2f(v4[2]) + bf2f(v5[2])) + (bf2f(v6[2]) + bf2f(v7[2]));
        a3 += (bf2f(v0[3]) + bf2f(v1[3])) + (bf2f(v2[3]) + bf2f(v3[3])) + (bf2f(v4[3]) + bf2f(v5[3])) + (bf2f(v6[3]) + bf2f(v7[3]));
        a4 += (bf2f(v0[4]) + bf2f(v1[4])) + (bf2f(v2[4]) + bf2f(v3[4])) + (bf2f(v4[4]) + bf2f(v5[4])) + (bf2f(v6[4]) + bf2f(v7[4]));
        a5 += (bf2f(v0[5]) + bf2f(v1[5])) + (bf2f(v2[5]) + bf2f(v3[5])) + (bf2f(v4[5]) + bf2f(v5[5])) + (bf2f(v6[5]) + bf2f(v7[5]));
        a6 += (bf2f(v0[6]) + bf2f(v1[6])) + (bf2f(v2[6]) + bf2f(v3[6])) + (bf2f(v4[6]) + bf2f(v5[6])) + (bf2f(v6[6]) + bf2f(v7[6]));
        a7 += (bf2f(v0[7]) + bf2f(v1[7])) + (bf2f(v2[7]) + bf2f(v3[7])) + (bf2f(v4[7]) + bf2f(v5[7])) + (bf2f(v6[7]) + bf2f(v7[7]));
    }
    float dn = dinv[n];
    const float4* __restrict__ b4 = (const float4*)bias;
    float4 bl0 = b4[li * 2], bl1 = b4[li * 2 + 1];
    ushort8 o;
    o[0] = f2bf(fmaxf(fmaf(a0, dn, bl0.x), 0.f));
    o[1] = f2bf(fmaxf(fmaf(a1, dn, bl0.y), 0.f));
    o[2] = f2bf(fmaxf(fmaf(a2, dn, bl0.z), 0.f));
    o[3] = f2bf(fmaxf(fmaf(a3, dn, bl0.w), 0.f));
    o[4] = f2bf(fmaxf(fmaf(a4, dn, bl1.x), 0.f));
    o[5] = f2bf(fmaxf(fmaf(a5, dn, bl1.y), 0.f));
    o[6] = f2bf(fmaxf(fmaf(a6, dn, bl1.z), 0.f));
    o[7] = f2bf(fmaxf(fmaf(a7, dn, bl1.w), 0.f));
    ((ushort8*)Bout)[(size_t)n * 16 + li] = o;
}

// ---------------- MFMA GEMM (layers 2,3): A' = bf16((Bb @ W) * dinv[row]) ----------------

__global__ __launch_bounds__(256) void k_gemm_mfma(const unsigned short* __restrict__ H,
                                                   const unsigned short* __restrict__ WT,
                                                   const float* __restrict__ dinv,
                                                   unsigned short* __restrict__ A, int N) {
    __shared__ float ep[4 * 16 * 132];  // per-wave 16x128 f32, row stride 132
    int tid = threadIdx.x, w = tid >> 6, l = tid & 63;
    int rbase = blockIdx.x * 64 + w * 16;
    int lrow = l & 15, lk = l >> 4;

    int r = rbase + lrow;
    if (r >= N) r = N - 1;
    const short8* __restrict__ Hp = (const short8*)(H + (size_t)r * 128);
    short8 af[4];
#pragma unroll
    for (int kc = 0; kc < 4; kc++) af[kc] = Hp[kc * 4 + lk];

    f32x4 acc[8];
#pragma unroll
    for (int t = 0; t < 8; t++) {
        f32x4 a = {0.f, 0.f, 0.f, 0.f};
        const short8* __restrict__ Wp = (const short8*)(WT + (size_t)(t * 16 + lrow) * 128);
#pragma unroll
        for (int kc = 0; kc < 4; kc++) {
            short8 bf = Wp[kc * 4 + lk];
            a = __builtin_amdgcn_mfma_f32_16x16x32_bf16(af[kc], bf, a, 0, 0, 0);
        }
        acc[t] = a;
    }

    float* base = ep + w * 2112;
#pragma unroll
    for (int t = 0; t < 8; t++)
#pragma unroll
        for (int j = 0; j < 4; j++)
            base[(4 * lk + j) * 132 + t * 16 + lrow] = acc[t][j];
    __syncthreads();

    int row16 = l >> 2, c0 = (l & 3) * 32;
    int orow = rbase + row16;
    if (orow < N) {
        float dn = dinv[orow];
        const float* src = base + row16 * 132 + c0;
        unsigned short* dst = A + (size_t)orow * 128 + c0;
#pragma unroll
        for (int q = 0; q < 4; q++) {
            union { short8 s8; unsigned short u[8]; } pk;
#pragma unroll
            for (int e = 0; e < 8; e++) pk.u[e] = f2bf(src[q * 8 + e] * dn);
            *(short8*)(dst + q * 8) = pk.s8;
        }
    }
}

// ---------------- Pool (vectorized): thread = (col-group of 8, row h of 32) ----------------

__global__ __launch_bounds__(512) void k_pool(const unsigned short* __restrict__ B, const int* __restrict__ batch,
                                              const float* __restrict__ Wl, const float* __restrict__ bl,
                                              float* __restrict__ out, int N) {
    int g = blockIdx.x;
    int tid = threadIdx.x;
    int k8 = tid & 15, h = tid >> 4;  // k8: 8-col group, h in 0..31
    __shared__ int se[2];
    __shared__ float red[32][128];
    if (tid < 2) {
        int target = g + tid;  // lower_bound(batch, target)
        int lo = 0, hi = N;
        while (lo < hi) {
            int mid = (lo + hi) >> 1;
            if (batch[mid] < target) lo = mid + 1; else hi = mid;
        }
        se[tid] = lo;
    }
    __syncthreads();
    int start = se[0], end = se[1];
    float s[8] = {};
    for (int n = start + h; n < end; n += 32) {
        ushort8 v = *(const ushort8*)(B + (size_t)n * 128 + k8 * 8);
#pragma unroll
        for (int j = 0; j < 8; j++) s[j] += bf2f(v[j]);
    }
#pragma unroll
    for (int j = 0; j < 8; j++) red[h][k8 * 8 + j] = s[j];
    __syncthreads();
    for (int off = 16; off >= 1; off >>= 1) {
        if (h < off) {
#pragma unroll
            for (int j = 0; j < 8; j++) red[h][k8 * 8 + j] += red[h + off][k8 * 8 + j];
        }
        __syncthreads();
    }
    if (h == 0) {
        int cg = end - start;
        float inv = 1.0f / (float)(cg > 1 ? cg : 1);
#pragma unroll
        for (int j = 0; j < 8; j++) red[0][k8 * 8 + j] *= inv;
    }
    __syncthreads();
    if (tid < 10) {
        float o = bl[tid];
        for (int j = 0; j < 128; j++) o = fmaf(red[0][j], Wl[j * 10 + tid], o);
        out[g * 10 + tid] = o;
    }
}

// ---------------- launch ----------------

extern "C" void kernel_launch(void* const* d_in, const int* in_sizes, int n_in,
                              void* d_out, int out_size, void* d_ws, size_t ws_size,
                              hipStream_t stream) {
    const float* x  = (const float*)d_in[0];
    const int* eidx = (const int*)d_in[1];
    const int* batch = (const int*)d_in[2];
    const float* W0 = (const float*)d_in[3];
    const float* b0 = (const float*)d_in[4];
    const float* W1 = (const float*)d_in[5];
    const float* b1 = (const float*)d_in[6];
    const float* W2 = (const float*)d_in[7];
    const float* b2 = (const float*)d_in[8];
    const float* Wl = (const float*)d_in[9];
    const float* bl = (const float*)d_in[10];

    int N = in_sizes[0] / 128;
    int E = in_sizes[1] / 2;
    int G = out_size / 10;
    const int* row = eidx;      // edge_index[0] = source
    const int* col = eidx + E;  // edge_index[1] = target

    char* w = (char*)d_ws;
    auto carve = [&](size_t bytes) -> void* {
        void* p = (void*)w;
        w += (bytes + 511) & ~(size_t)511;
        return p;
    };
    unsigned short* A  = (unsigned short*)carve((size_t)(N + 1) * 128 * 2);  // bf16, +zero row N
    unsigned short* Bb = (unsigned short*)carve((size_t)N * 128 * 2);        // bf16
    int*   cnt  = (int*)carve((size_t)N * 4);
    float* dinv = (float*)carve((size_t)N * 4);
    int*   ell  = (int*)carve((size_t)N * ELL_D * 4);
    unsigned short* WT1 = (unsigned short*)carve(16384 * 2);
    unsigned short* WT2 = (unsigned short*)carve(16384 * 2);

    int gb = (N + 63) / 64;
    int ft = (E + 7) / 8;
    int fb = (ft + 255) / 256;
    int M  = (gb > fb) ? gb : fb;

    hipMemsetAsync(cnt, 0, (size_t)N * 4, stream);
    // prep_wt (blocks 0,1) + layer-1 gemm (f32 vector) + ELL fill, one fat kernel
    k_fused<<<2 * M + 2, 256, 0, stream>>>(x, W0, A, col, row, cnt, ell, W1, W2, WT1, WT2, N, E, gb, fb);
    // dinv + scale A + pad ELL (self + N-sentinels to x8) + zero row N
    k_scaleA_pad<<<(N + 7) / 8, 256, 0, stream>>>(cnt, dinv, A, ell, N);

    int ab = (N + 15) / 16;
    int mb = (N + 63) / 64;
    k_agg<<<ab, 256, 0, stream>>>(A, cnt, ell, dinv, b0, Bb, N);
    // layer 2
    k_gemm_mfma<<<mb, 256, 0, stream>>>(Bb, WT1, dinv, A, N);
    k_agg<<<ab, 256, 0, stream>>>(A, cnt, ell, dinv, b1, Bb, N);
    // layer 3
    k_gemm_mfma<<<mb, 256, 0, stream>>>(Bb, WT2, dinv, A, N);
    k_agg<<<ab, 256, 0, stream>>>(A, cnt, ell, dinv, b2, Bb, N);
    // pool + head
    k_pool<<<G, 512, 0, stream>>>(Bb, batch, Wl, bl, (float*)d_out, N);
}